// Round 5
// baseline (474.212 us; speedup 1.0000x reference)
//
#include <hip/hip_runtime.h>
#include <hip/hip_bf16.h>

#define NN 8192
#define DIM 128
#define BM 16
#define BK 64
#define NT (NN / BK)

typedef __attribute__((ext_vector_type(4))) float f32x4;
typedef __attribute__((ext_vector_type(8))) short bf16x8;
typedef __attribute__((ext_vector_type(4))) short bf16x4;

static __device__ __forceinline__ short f2bf(float f) {
    __hip_bfloat16 h = __float2bfloat16(f);
    return *reinterpret_cast<short*>(&h);
}
static __device__ __forceinline__ float bf2f(short s) {
    union { unsigned int u; float f; } c;
    c.u = ((unsigned int)(unsigned short)s) << 16;
    return c.f;
}

// async global->LDS, 16 bytes per lane; dst must be linear: wave base + lane*16
static __device__ __forceinline__ void gload16(const void* g, void* l) {
    __builtin_amdgcn_global_load_lds(
        (const __attribute__((address_space(1))) unsigned int*)g,
        (__attribute__((address_space(3))) unsigned int*)l, 16, 0, 0);
}

// ---------------- kernel 1: degree row-sums -> d^{-1/2} ----------------
__global__ __launch_bounds__(256) void k_rowsum(const float* __restrict__ A,
                                                float* __restrict__ dinv) {
    const int row = blockIdx.x;
    const int t = threadIdx.x;
    const float4* a4 = reinterpret_cast<const float4*>(A + (size_t)row * NN);
    float s = 0.f;
#pragma unroll
    for (int q = 0; q < 8; ++q) {
        float4 v = a4[q * 256 + t];
        s += (v.x + v.y) + (v.z + v.w);
    }
#pragma unroll
    for (int off = 32; off > 0; off >>= 1) s += __shfl_down(s, off);
    __shared__ float red[4];
    if ((t & 63) == 0) red[t >> 6] = s;
    __syncthreads();
    if (t == 0) {
        float deg = red[0] + red[1] + red[2] + red[3] + 1.0f;   // +I self-loop
        dinv[row] = 1.0f / sqrtf(deg);
    }
}

// ------- kernel 2: Yt[f'][j] = bf16( dinv[j] * sum_f X[j][f] * W[f'][f] ) -------
__global__ __launch_bounds__(256) void k_y(const float* __restrict__ X,
                                           const float* __restrict__ W,
                                           const float* __restrict__ dinv,
                                           short* __restrict__ Yt) {
    __shared__ float Wl[64 * 128];
    __shared__ float Xl[32 * 129];   // +1 pad: conflict-free lane=j reads
    const int t = threadIdx.x;
    const int j0 = (blockIdx.x >> 1) * 32;
    const int half = blockIdx.x & 1;

    const float4* wg = reinterpret_cast<const float4*>(W + (size_t)half * 64 * 128);
#pragma unroll
    for (int q = 0; q < 8; ++q)
        reinterpret_cast<float4*>(Wl)[q * 256 + t] = wg[q * 256 + t];
#pragma unroll
    for (int q = 0; q < 4; ++q) {
        int p = q * 256 + t;
        int row = p >> 5, c4 = p & 31;
        float4 v = reinterpret_cast<const float4*>(X + (size_t)(j0 + row) * DIM)[c4];
        float* dst = Xl + row * 129 + c4 * 4;
        dst[0] = v.x; dst[1] = v.y; dst[2] = v.z; dst[3] = v.w;
    }
    __syncthreads();

    const int j = t & 31;
    const int fb = t >> 5;             // 0..7
    const float dj = dinv[j0 + j];
    float acc[8];
#pragma unroll
    for (int k = 0; k < 8; ++k) acc[k] = 0.f;
    for (int f = 0; f < DIM; ++f) {
        float xv = Xl[j * 129 + f];
#pragma unroll
        for (int k = 0; k < 8; ++k)
            acc[k] = fmaf(xv, Wl[(fb + k * 8) * 128 + f], acc[k]);
    }
#pragma unroll
    for (int k = 0; k < 8; ++k)
        Yt[(size_t)(half * 64 + fb + k * 8) * NN + j0 + j] = f2bf(dj * acc[k]);
}

// ---------------- kernel 3: out = dinv[i]*( (A @ Y)[i,f] + Y[i,f] ) + b[f] ----------------
// BM=16 -> grid 512 (2 blocks/CU for TLP). 512 threads = 8 waves, each wave one 16x16 out tile.
// Yt staged via global_load_lds with pre-swizzled source; A reg-staged with depth-2 prefetch.
__global__ __launch_bounds__(512, 4) void k_main(const float* __restrict__ A,
                                                 const short* __restrict__ Yt,
                                                 const float* __restrict__ dinv,
                                                 const float* __restrict__ bias,
                                                 float* __restrict__ out) {
    __shared__ short Ab[2][BM * BK];    // [16][64] bf16, rows 128 B, XOR-swizzled
    __shared__ short Yb[2][DIM * BK];   // [128][64] bf16, rows 128 B, XOR-swizzled

    const int t = threadIdx.x;
    const int i0 = blockIdx.x * BM;

    // ---- A staging (threads 0..255): row ar, float4 chunk ac4 ----
    const int ar = t >> 4;                 // 0..15 (t<256)
    const int ac4 = t & 15;                // 0..15
    const float4* aG = reinterpret_cast<const float4*>(A + (size_t)(i0 + (ar & 15)) * NN) + ac4;
    const int aLoff = ar * 128 + ((ac4 * 8) ^ ((ar & 7) << 4));   // bytes

    // ---- Yt staging via global_load_lds: linear dst = t*16, pre-swizzled src chunk ----
    const int yRow0 = t >> 3;                       // 0..63
    const int ychunk = (t & 7) ^ (yRow0 & 7);       // pre-swizzle 16-B chunk index
    const short* ySrc0 = Yt + (size_t)yRow0 * NN + ychunk * 8;
    const short* ySrc1 = Yt + (size_t)(yRow0 + 64) * NN + ychunk * 8;   // (row+64)&7 == row&7

    // ---- fragment read offsets ----
    const int lane = t & 63;
    const int wid = t >> 6;                // 0..7 = wave's 16-col group
    const int l15 = lane & 15, lk = lane >> 4;
    const int f = wid * 16 + l15;
    const int swzA = (l15 & 7) << 4;       // (f&7)==(l15&7) too, 16 | 8
    int offA[2], offB[2];
#pragma unroll
    for (int kc = 0; kc < 2; ++kc) {
        const int bcol = kc * 64 + lk * 16;
        offA[kc] = l15 * 128 + (bcol ^ swzA);
        offB[kc] = f * 128 + (bcol ^ swzA);
    }

    f32x4 acc = {0.f, 0.f, 0.f, 0.f};

    // ---- prologue: stage tile 0; prefetch A tile 1 into regs ----
    gload16(ySrc0, (char*)Yb[0] + t * 16);
    gload16(ySrc1, (char*)Yb[0] + 8192 + t * 16);
    float4 avCur;
    if (t < 256) {
        float4 av0 = aG[0];
        bf16x4 a16 = { f2bf(av0.x), f2bf(av0.y), f2bf(av0.z), f2bf(av0.w) };
        *reinterpret_cast<bf16x4*>(reinterpret_cast<char*>(Ab[0]) + aLoff) = a16;
        avCur = aG[(NT > 1 ? 1 : 0) * 16];
    }
    __syncthreads();

    int cur = 0;
    for (int kt = 0; kt < NT; ++kt) {
        const int nxt  = (kt + 1 < NT) ? kt + 1 : NT - 1;
        const int nxt2 = (kt + 2 < NT) ? kt + 2 : NT - 1;

        // issue Yt loads for tile nxt directly into the other LDS buffer
        char* ybw = reinterpret_cast<char*>(Yb[cur ^ 1]);
        gload16(ySrc0 + (size_t)nxt * BK, ybw + t * 16);
        gload16(ySrc1 + (size_t)nxt * BK, ybw + 8192 + t * 16);

        // issue A load for tile nxt+1 (depth-2)
        float4 avN;
        if (t < 256) avN = aG[nxt2 * 16];

        // compute current tile
        const char* ab = reinterpret_cast<const char*>(Ab[cur]);
        const char* yb = reinterpret_cast<const char*>(Yb[cur]);
        bf16x8 a0 = *reinterpret_cast<const bf16x8*>(ab + offA[0]);
        bf16x8 a1 = *reinterpret_cast<const bf16x8*>(ab + offA[1]);
        bf16x8 b0 = *reinterpret_cast<const bf16x8*>(yb + offB[0]);
        bf16x8 b1 = *reinterpret_cast<const bf16x8*>(yb + offB[1]);
        acc = __builtin_amdgcn_mfma_f32_16x16x32_bf16(a0, b0, acc, 0, 0, 0);
        acc = __builtin_amdgcn_mfma_f32_16x16x32_bf16(a1, b1, acc, 0, 0, 0);

        // write A tile nxt (loaded 2 iters ago pipeline-wise) into the other buffer
        if (t < 256) {
            bf16x4 a16 = { f2bf(avCur.x), f2bf(avCur.y), f2bf(avCur.z), f2bf(avCur.w) };
            *reinterpret_cast<bf16x4*>(reinterpret_cast<char*>(Ab[cur ^ 1]) + aLoff) = a16;
            avCur = avN;
        }
        __syncthreads();
        cur ^= 1;
    }

    // ---- epilogue: out[i][f] = dinv[i]*(acc + Y[i][f]) + b[f] ----
    const int iBase = i0 + lk * 4;
    const float4 dv4 = *reinterpret_cast<const float4*>(dinv + iBase);
    const float dvr[4] = { dv4.x, dv4.y, dv4.z, dv4.w };
    const float bf_ = bias[f];
    bf16x4 yv = *reinterpret_cast<const bf16x4*>(Yt + (size_t)f * NN + iBase);
#pragma unroll
    for (int r = 0; r < 4; ++r) {
        float z = acc[r] + bf2f(yv[r]);
        out[(size_t)(iBase + r) * DIM + f] = dvr[r] * z + bf_;
    }
}

extern "C" void kernel_launch(void* const* d_in, const int* in_sizes, int n_in,
                              void* d_out, int out_size, void* d_ws, size_t ws_size,
                              hipStream_t stream) {
    (void)in_sizes; (void)n_in; (void)out_size; (void)ws_size;
    const float* X = (const float*)d_in[0];
    const float* A = (const float*)d_in[1];
    const float* W = (const float*)d_in[2];
    const float* b = (const float*)d_in[3];
    float* out = (float*)d_out;

    float* dinv = (float*)d_ws;                                  // 8192 f32
    short* Yt = (short*)((char*)d_ws + NN * sizeof(float));      // [128][8192] bf16

    k_rowsum<<<NN, 256, 0, stream>>>(A, dinv);
    k_y<<<(NN / 32) * 2, 256, 0, stream>>>(X, W, dinv, Yt);
    k_main<<<NN / BM, 512, 0, stream>>>(A, Yt, dinv, b, out);
}